// Round 2
// baseline (179.795 us; speedup 1.0000x reference)
//
#include <hip/hip_runtime.h>
#include <hip/hip_fp16.h>

// TriLinear 3D-LUT apply: lut (3,33,33,33) f32, img (4,3,1080,1920) f32
// -> out (4,3,1080,1920) f32.
//
// History:
//  R1: LDS-packed LUT, 97 us — latency-bound, serialized gathers (VGPR=64).
//  R3: ILP restructure + img prefetch + persistent blocks -> kernel < 59 us.
//  R4: prepass-quantized LUT + dwordx4 LDS staging -> total 183.1 us.
//  R5: byte LUT + v_perm pair-decode + pk-f16 lerps -> total 181.7 us (-1.4;
//      VALU halving barely moved time => NOT VALU-bound; latency-bound).
//  R6: 2-deep software pipeline @ BLOCK=512 -> 182.3 us (pipeline bought with
//      occupancy — 2 waves/SIMD can't hide the residual stalls).
//  R7: BLOCK=768 + launch_bounds(768,3) (12 waves/CU) + global_load_lds
//      staging -> 177.6 us. Occupancy is the lever that works; still
//      latency-bound (no pipe near saturation: HBM ~32us, LDS ~7us, VALU
//      ~14us vs ~53us observed).
//  R8 (this): BLOCK=1024 (16 waves/CU = 4/SIMD, the LDS-allowed max).
//   - 1024 threads @ 4 waves/EU caps VGPR at 128; the 4-px 2-deep pipeline
//     state (~140 regs) doesn't fit, so the work unit shrinks to 2 px per
//     thread-iteration: Frag state halves (cc[2][8]), total live state
//     ~70-80 VGPR. VMEM goes dwordx4 -> dwordx2 (still 512 B/wave,
//     coalesced); ds_read2 count per unit halves -> finer pipeline stages.
//   - keeps: 2-deep software pipeline, byte-LUT + v_perm + pk-f16 blend,
//     global_load_lds LUT staging, persistent 1-block/CU grid.

namespace {
constexpr int D_    = 33;
constexpr int D2_   = D_ * D_;        // 1089
constexpr int LUT_N = D_ * D_ * D_;   // 35937
constexpr int HW    = 1080 * 1920;    // 2073600
constexpr int UPB   = HW / 2;         // 1036800 2-px units per (batch) plane
constexpr int NUNITS = 4 * UPB;       // 4147200
constexpr int BLOCK = 1024;
constexpr int GRID  = 256;            // 1 persistent block per CU
constexpr int TSTRIDE = GRID * BLOCK; // 262144 -> ~15.8 iters/thread
}

typedef float v2f  __attribute__((ext_vector_type(2)));
typedef unsigned int v4u __attribute__((ext_vector_type(4)));

__device__ __forceinline__ unsigned int quant3(float r, float g, float b) {
    unsigned int qr = (unsigned int)(fminf(fmaxf(r, 0.f), 1.f) * 255.f + 0.5f);
    unsigned int qg = (unsigned int)(fminf(fmaxf(g, 0.f), 1.f) * 255.f + 0.5f);
    unsigned int qb = (unsigned int)(fminf(fmaxf(b, 0.f), 1.f) * 255.f + 0.5f);
    return qr | (qg << 8) | (qb << 16);
}

// ---- pre-pass: quantize + byte-pack the LUT into d_ws (LUT_N dwords) ----
__global__ __launch_bounds__(256)
void quantize_lut_kernel(const float* __restrict__ lut,
                         unsigned int* __restrict__ packed) {
    int i = blockIdx.x * 256 + threadIdx.x;
    if (i < LUT_N)
        packed[i] = quant3(lut[i], lut[i + LUT_N], lut[i + 2 * LUT_N]);
}

struct Img  { v2f x, y, z; int base; };
struct Frag {
    unsigned int cc[2][8];
    __half2 fxh, fyh;
    float fz[2];
    int base;
};

__device__ __forceinline__ void loadImg(const float* __restrict__ img, int u,
                                        Img& im) {
    int b  = u / UPB;
    int r2 = u - b * UPB;
    im.base = b * 3 * HW + r2 * 2;
    im.x = __builtin_nontemporal_load((const v2f*)(img + im.base));
    im.y = __builtin_nontemporal_load((const v2f*)(img + im.base + HW));
    im.z = __builtin_nontemporal_load((const v2f*)(img + im.base + 2 * HW));
}

// stage1 (indices/fractions) + issue all 8 LDS gather-pairs for one 2-px unit
__device__ __forceinline__ void makeFrag(const unsigned int* __restrict__ slut,
                                         const Img& im, Frag& f) {
    f.base = im.base;
    float fx[2], fy[2];
    int bidx[2];
#pragma unroll
    for (int j = 0; j < 2; ++j) {
        float px = im.x[j] * 32.f;
        float py = im.y[j] * 32.f;
        float pz = im.z[j] * 32.f;
        int ix = (int)px, iy = (int)py, iz = (int)pz;
        fx[j]   = px - (float)ix;
        fy[j]   = py - (float)iy;
        f.fz[j] = pz - (float)iz;
        bidx[j] = iz * D2_ + iy * D_ + ix;
    }
#pragma unroll
    for (int j = 0; j < 2; ++j) {
        int b0 = bidx[j];
        int b1 = b0 + D2_;
        f.cc[j][0] = slut[b0];        f.cc[j][1] = slut[b0 + 1];
        f.cc[j][2] = slut[b0 + D_];   f.cc[j][3] = slut[b0 + D_ + 1];
        f.cc[j][4] = slut[b1];        f.cc[j][5] = slut[b1 + 1];
        f.cc[j][6] = slut[b1 + D_];   f.cc[j][7] = slut[b1 + D_ + 1];
    }
    f.fxh = __floats2half2_rn(fx[0], fx[1]);
    f.fyh = __floats2half2_rn(fy[0], fy[1]);
}

__device__ __forceinline__ __half2 lerp2(__half2 lo, __half2 hi, __half2 fr) {
    return __hfma2(fr, __hsub2(hi, lo), lo);
}

// pk-f16 blend of one 2-px unit + nontemporal store
__device__ __forceinline__ void blendStore(const Frag& f,
                                           float* __restrict__ out) {
    float outv[3][2];
    const __half2 fhx = f.fxh;
    const __half2 fhy = f.fyh;
    const float fz0 = f.fz[0], fz1 = f.fz[1];
#pragma unroll
    for (int c = 0; c < 3; ++c) {
        // dst byte0 = cc[0] byte c (sel 4+c), byte1 = 0 (sel 0x0C),
        // dst byte2 = cc[1] byte c (sel c),   byte3 = 0 (sel 0x0C)
        const unsigned int sel = 0x0C000C04u | ((unsigned)c << 16) | (unsigned)c;
        __half2 h[8];
#pragma unroll
        for (int k = 0; k < 8; ++k) {
            union { unsigned int u; __half2 h2; } t;
            t.u = __builtin_amdgcn_perm(f.cc[0][k], f.cc[1][k], sel) | 0x5C005C00u;
            h[k] = t.h2;   // {256 + n_px0/4, 256 + n_px1/4} exactly in f16
        }
        __half2 x00 = lerp2(h[0], h[1], fhx);
        __half2 x01 = lerp2(h[2], h[3], fhx);
        __half2 x10 = lerp2(h[4], h[5], fhx);
        __half2 x11 = lerp2(h[6], h[7], fhx);
        __half2 y0  = lerp2(x00, x01, fhy);
        __half2 y1  = lerp2(x10, x11, fhy);
        float y0a = __low2float(y0), y0b = __high2float(y0);
        float y1a = __low2float(y1), y1b = __high2float(y1);
        float za = fmaf(fz0, y1a - y0a, y0a);
        float zb = fmaf(fz1, y1b - y0b, y0b);
        outv[c][0] = fmaf(za, 4.0f / 255.0f, -1024.0f / 255.0f);
        outv[c][1] = fmaf(zb, 4.0f / 255.0f, -1024.0f / 255.0f);
    }
    v2f ro = {outv[0][0], outv[0][1]};
    v2f go = {outv[1][0], outv[1][1]};
    v2f bo = {outv[2][0], outv[2][1]};
    __builtin_nontemporal_store(ro, (v2f*)(out + f.base));
    __builtin_nontemporal_store(go, (v2f*)(out + f.base + HW));
    __builtin_nontemporal_store(bo, (v2f*)(out + f.base + 2 * HW));
}

template <bool PACKED>
__global__ __launch_bounds__(BLOCK, 4)
void trilut_kernel(const float* __restrict__ lut,
                   const unsigned int* __restrict__ packed,
                   const float* __restrict__ img,
                   float* __restrict__ out) {
    __shared__ unsigned int slut[LUT_N];   // 143748 B -> 1 block/CU, 16 waves

    Img  im0, im1;
    Frag fg0, fg1;

    // prologue: img loads for iter 0 and 1 issued BEFORE LUT staging so their
    // HBM latency hides under the staging DMA + barrier drain.
    int u0 = blockIdx.x * BLOCK + threadIdx.x;   // < 262144 < NUNITS always
    loadImg(img, u0, im0);
    int u1 = u0 + TSTRIDE;
    bool v1 = u1 < NUNITS;
    if (v1) loadImg(img, u1, im1);

    if (PACKED) {
        // global -> LDS DMA, 16B per lane per issue; destination is linear
        // (wave-uniform base + lane*16), which matches this layout exactly.
        constexpr int NCH = LUT_N / 4;     // 8984 16B chunks + 1 tail dword
        const int lane = threadIdx.x & 63;
        for (int c = threadIdx.x; c < NCH; c += BLOCK) {
            const unsigned int* gsrc = packed + c * 4;
            unsigned int* ldst = slut + (c - lane) * 4;   // wave-uniform base
            __builtin_amdgcn_global_load_lds(
                (const __attribute__((address_space(1))) unsigned int*)gsrc,
                (__attribute__((address_space(3))) unsigned int*)ldst,
                16, 0, 0);
        }
        if (threadIdx.x == 0) slut[LUT_N - 1] = packed[LUT_N - 1];
    } else {
        for (int i = threadIdx.x; i < LUT_N; i += BLOCK)
            slut[i] = quant3(lut[i], lut[i + LUT_N], lut[i + 2 * LUT_N]);
    }
    __syncthreads();   // drains vmcnt(0): staging DMA + im0/im1 all complete

    makeFrag(slut, im0, fg0);              // gathers for iter 0 in flight

    // steady state at body top (parity s): fg[s] gathered, im[s^1] holds
    // img for the next iter, load target im[s] is free.
    while (true) {
        {   // s = 0: blend fg0; produce fg1 from im1; load n+2 -> im0
            int u2 = u1 + TSTRIDE; bool v2 = u2 < NUNITS;
            if (v2) loadImg(img, u2, im0);
            if (v1) makeFrag(slut, im1, fg1);
            blendStore(fg0, out);
            if (!v1) return;
            u1 = u2; v1 = v2;
        }
        {   // s = 1: blend fg1; produce fg0 from im0; load n+2 -> im1
            int u2 = u1 + TSTRIDE; bool v2 = u2 < NUNITS;
            if (v2) loadImg(img, u2, im1);
            if (v1) makeFrag(slut, im0, fg0);
            blendStore(fg1, out);
            if (!v1) return;
            u1 = u2; v1 = v2;
        }
    }
}

extern "C" void kernel_launch(void* const* d_in, const int* in_sizes, int n_in,
                              void* d_out, int out_size, void* d_ws, size_t ws_size,
                              hipStream_t stream) {
    const float* lut = (const float*)d_in[0];
    const float* img = (const float*)d_in[1];
    float* out = (float*)d_out;

    if (ws_size >= (size_t)LUT_N * sizeof(unsigned int)) {
        unsigned int* packed = (unsigned int*)d_ws;
        quantize_lut_kernel<<<(LUT_N + 255) / 256, 256, 0, stream>>>(lut, packed);
        trilut_kernel<true><<<GRID, BLOCK, 0, stream>>>(lut, packed, img, out);
    } else {
        trilut_kernel<false><<<GRID, BLOCK, 0, stream>>>(lut, nullptr, img, out);
    }
}